// Round 1
// baseline (70.919 us; speedup 1.0000x reference)
//
#include <hip/hip_runtime.h>

// PackedStdScaler: grouped (sample_id, variate_id) masked mean/std over (B,S,D)
// B=4, S=2048, D=128; ids in [0,8) -> 64 groups/batch, 768 accumulator doubles.
//
// Restructure vs previous version (66.2us): the old single kernel had every
// block re-scan ids + ballot-compact a row list + 4 barriers + serial epilogue
// at 1 block/CU -> latency-bound (~25us kernel vs ~0.8us ideal traffic).
// New: memset(6KiB ws) -> K1 (wave-per-row accumulate, f64 HW atomics)
//                      -> K2 (thread-per-row finalize+scatter).
// Rows read exactly once, no compaction, no dependent LDS->global chains.

#define BB 4
#define SS 2048
#define DD 128
#define NROW (BB * SS)       // 8192
#define NG 64                // groups per batch
#define NSLOT (BB * NG * 3)  // 768 doubles = 6144 B of ws

#define K1_BLOCKS 256
#define K1_NT 512
#define K1_NW (K1_NT / 64)              // 8 waves/block
#define K1_WAVES (K1_BLOCKS * K1_NW)    // 2048 waves
#define ROWS_PER_WAVE (NROW / K1_WAVES) // 4 consecutive rows per wave

__global__ __launch_bounds__(K1_NT) void pss_accum(
    const float* __restrict__ target,
    const unsigned* __restrict__ mask_raw,   // raw words of observed_mask
    const int* __restrict__ sample_id,
    const int* __restrict__ variate_id,
    double* __restrict__ ws)                 // [B][NG][3] = cnt, sum, sumsq
{
    const int tid  = threadIdx.x;
    const int lane = tid & 63;
    const int wave = tid >> 6;

    // mask dtype detection: byte-bool buffer => some of first 64 words > 1.
    // One wave, one ballot, one plain LDS store (no 512-way atomic serialize).
    __shared__ int mflag;
    if (tid < 64) {
        const unsigned long long bal = __ballot(mask_raw[tid] > 1u);
        if (tid == 0) mflag = (bal != 0ull) ? 1 : 0;
    }
    __syncthreads();
    const bool bytemask = (mflag != 0);

    const int gw = blockIdx.x * K1_NW + wave;   // global wave id [0, 2048)
    const int r0 = gw * ROWS_PER_WAVE;          // 4 consecutive rows

    #pragma unroll
    for (int k = 0; k < ROWS_PER_WAVE; ++k) {
        const int r   = r0 + k;                 // row in [0, 8192)
        const int b   = r >> 11;                // r / SS
        const int key = sample_id[r] * 8 + variate_id[r];   // broadcast loads
        const size_t off = (size_t)r * DD;

        const float2 tv = ((const float2*)(target + off))[lane];
        int m0, m1;
        if (bytemask) {
            const uchar2 mv =
                ((const uchar2*)((const unsigned char*)mask_raw + off))[lane];
            m0 = mv.x; m1 = mv.y;
        } else {
            const int2 mv =
                ((const int2*)((const int*)mask_raw + off))[lane];
            m0 = mv.x; m1 = mv.y;
        }

        float  c  = 0.f;
        double s1 = 0.0, s2 = 0.0;
        if (m0) { c += 1.f; s1 += (double)tv.x; s2 += (double)tv.x * (double)tv.x; }
        if (m1) { c += 1.f; s1 += (double)tv.y; s2 += (double)tv.y * (double)tv.y; }

        // 64-lane wave reduction of (c, s1, s2)
        for (int o = 32; o > 0; o >>= 1) {
            c  += __shfl_down(c,  o, 64);
            s1 += __shfl_down(s1, o, 64);
            s2 += __shfl_down(s2, o, 64);
        }

        if (lane == 0) {
            double* slot = ws + (size_t)(b * NG + key) * 3;
            // native global_atomic_add_f64 (device scope) — no CAS loop
            unsafeAtomicAdd(slot + 0, (double)c);
            unsafeAtomicAdd(slot + 1, s1);
            unsafeAtomicAdd(slot + 2, s2);
        }
    }
}

#define K2_NT 256

__global__ __launch_bounds__(K2_NT) void pss_finalize(
    const int* __restrict__ sample_id,
    const int* __restrict__ variate_id,
    const double* __restrict__ ws,
    float* __restrict__ out)   // [0,NROW): loc, [NROW,2*NROW): scale
{
    const int r   = blockIdx.x * K2_NT + threadIdx.x;  // exact: 32*256 = 8192
    const int b   = r >> 11;
    const int sd  = sample_id[r];
    const int key = sd * 8 + variate_id[r];

    const double* slot = ws + (size_t)(b * NG + key) * 3;  // 6 KiB, L2-hot
    const double cnt = slot[0], gs = slot[1], gss = slot[2];

    // safe_div semantics: den==0 -> divide by 1
    const double loc = gs / (cnt == 0.0 ? 1.0 : cnt);
    double varnum = gss - 2.0 * loc * gs + loc * loc * cnt; // == sum((t-loc)^2*obs)
    if (varnum < 0.0) varnum = 0.0;                         // fp cancellation guard
    const double den = cnt - 1.0;                           // CORRECTION = 1
    double var = varnum / (den == 0.0 ? 1.0 : den);
    if (var < 0.0) var = 0.0;

    float locf   = (float)loc;
    float scalef = (float)sqrt(var + 1e-5);                 // MINIMUM_SCALE
    if (sd == 0) { locf = 0.f; scalef = 1.f; }              // sample_id==0 padding

    out[r]        = locf;
    out[NROW + r] = scalef;
}

extern "C" void kernel_launch(void* const* d_in, const int* in_sizes, int n_in,
                              void* d_out, int out_size, void* d_ws, size_t ws_size,
                              hipStream_t stream) {
    const float*    target = (const float*)d_in[0];
    const unsigned* mask   = (const unsigned*)d_in[1];
    const int*      sid    = (const int*)d_in[2];
    const int*      vid    = (const int*)d_in[3];
    float*          out    = (float*)d_out;
    double*         ws     = (double*)d_ws;

    // zero the 768 accumulator doubles (graph-capture-safe memset node)
    hipMemsetAsync(ws, 0, NSLOT * sizeof(double), stream);

    hipLaunchKernelGGL(pss_accum, dim3(K1_BLOCKS), dim3(K1_NT), 0, stream,
                       target, mask, sid, vid, ws);

    hipLaunchKernelGGL(pss_finalize, dim3(NROW / K2_NT), dim3(K2_NT), 0, stream,
                       sid, vid, ws, out);
}